// Round 13
// baseline (11654.863 us; speedup 1.0000x reference)
//
#include <hip/hip_runtime.h>
#include <cmath>

typedef _Float16 f16;
typedef _Float16 f16x8 __attribute__((ext_vector_type(8)));
typedef float f32x4 __attribute__((ext_vector_type(4)));
typedef int i32x4 __attribute__((ext_vector_type(4)));
typedef unsigned long long u64;

#define NR 2048
#define NU 80
#define NUP 96          // NU padded to multiple of 32
#define NB 32           // batch
#define NS 1024         // seq len
#define NWG 64          // one WG per 32-col slice, all 32 batch rows
#define ALPHA 0.6f
#define SIGMA_B 1.6f
#define RETRY_BOUND (1 << 18)   // slow-path cap: deadlock -> diagnosable wrongness

// workspace layout (bytes)
#define OFF_AF   0ull                              // A fp16 [2048][2048] : 8 MiB
#define OFF_XP   (OFF_AF + (size_t)NR*NR*2)        // input fp16 [s][b][96] : 6 MiB
#define OFF_BP   (OFF_XP + (size_t)NS*NB*NUP*2)    // B fp16 [2048][96]
#define OFF_RB   (OFF_BP + (size_t)NR*NUP*2)       // r bufs fp16 [2][NB][NR] : 256 KiB

// step-parity tag in bit0 of EVERY published f16 (r12-validated).
// t(s) = ((s>>1)+1)&1 : slot occupants at steps s and s-2 always differ; prep
// tags r0 with t(0)=1; 0xAA poison (bit0=0) and replay leftovers are stale.
__device__ __host__ inline int tag_of_step(int s) { return (((s >> 1) + 1) & 1); }

__global__ void prep_kernel(const float* __restrict__ input,
                            const float* __restrict__ r0,
                            const float* __restrict__ A,
                            const float* __restrict__ B,
                            f16* __restrict__ Af, f16* __restrict__ xp,
                            f16* __restrict__ Bp, f16* __restrict__ rb)
{
    const int stride = gridDim.x * blockDim.x;
    const int tid = blockIdx.x * blockDim.x + threadIdx.x;
    for (int i = tid; i < NR * NR; i += stride) Af[i] = (f16)A[i];
    for (int i = tid; i < NS * NB * NUP; i += stride) {
        int u = i % NUP; int sb = i / NUP; int b = sb % NB; int s = sb / NB;
        xp[i] = (u < NU) ? (f16)input[((size_t)b * NS + s) * NU + u] : (f16)0.0f;
    }
    for (int i = tid; i < NR * NUP; i += stride) {
        int u = i % NUP; int j = i / NUP;
        Bp[i] = (u < NU) ? (f16)B[j * NU + u] : (f16)0.0f;
    }
    // r0 -> buffer 0, tagged t(0)=1
    for (int i = tid; i < NB * NR; i += stride) {
        f16 h = (f16)r0[i];
        unsigned short b = __builtin_bit_cast(unsigned short, h);
        b = (unsigned short)((b & ~1u) | 1u);
        rb[i] = __builtin_bit_cast(f16, b);
    }
}

#define MFMA(va, vb, vc) __builtin_amdgcn_mfma_f32_16x16x32_f16(va, vb, vc, 0, 0, 0)
#define TAGOF(v) (__builtin_bit_cast(i32x4, v).x & 1)
// Rule #18: bare s_waitcnt needs a following sched_barrier(0).
#define WAIT0 do { asm volatile("s_waitcnt vmcnt(0)" ::: "memory");            \
                   __builtin_amdgcn_sched_barrier(0); } while (0)

__device__ inline f16x8 pack16(u64 lo, u64 hi) {
    u64 t[2] = { lo, hi };
    f16x8 r;
    __builtin_memcpy(&r, t, 16);
    return r;
}

// Speculative tag-validated device-scope scan.
// 64 WGs x 256 threads; WG cg owns output cols [32cg,32cg+32) for all 32 batch
// rows. Wave kq consumes r cols [512kq,512kq+512) and owns output tile
// (rt=kq>>1, ct=kq&1); master state in f32 registers.
// Per step (NO detect poll, NO ack, NO flags):
//   issue 32x16B sc0sc1 asm loads STRAIGHT-LINE (proven-safe shape: single def,
//   never re-issued in a loop) -> WAIT0 -> verify 1 tag bit per 16B cell
//   (cells are whole dwordx4 publishes => per-cell atomic) ->
//   [cold slow path: bounded C++ atomic reload loop, overwrites after retire]
//   -> 64+3 MFMAs -> LDS reduce -> tanh -> tagged 16B fire-and-forget publish.
// Lap-safety (r12 argument): a WG publishes s+1 only after its 4 waves verified
// step-s tags from ALL 64 WGs (joined at the reduce barrier); producer tags for
// step s are stored after that producer's step-(s-1) reads completed, so no
// slot is overwritten while any reader still needs it.
__global__ __launch_bounds__(256, 1) void scan_kernel(
    float* __restrict__ out,
    const float* __restrict__ r0,
    const f16* __restrict__ Af, const f16* __restrict__ xp,
    const f16* __restrict__ Bp, f16* __restrict__ rbuf)
{
    const int tid  = threadIdx.x;
    const int lane = tid & 63;
    const int kq   = tid >> 6;      // K-quarter; owned tile = (kq>>1, kq&1)
    const int cg   = blockIdx.x;
    const int rt   = kq >> 1;
    const int ct   = kq & 1;
    const int fr   = lane & 15;
    const int kg   = lane >> 4;

    __shared__ f32x4 lds_part[4][4][64];   // [wave][tile][lane]
    __shared__ f16   lds_r[32 * 40];       // stride 40 halves (80B, 16B-aligned)

    // ---- A-slice -> registers (B^T fragment layout), 2 col-tiles x 16 k-frags
    f16x8 bf[2][16];
    #pragma unroll
    for (int c = 0; c < 2; ++c) {
        const f16* base = Af + (size_t)(cg * 32 + c * 16 + fr) * NR + kq * 512 + kg * 8;
        #pragma unroll
        for (int kk = 0; kk < 16; ++kk)
            bf[c][kk] = *(const f16x8*)(base + kk * 32);
    }
    #pragma unroll
    for (int c = 0; c < 2; ++c)
        #pragma unroll
        for (int kk = 0; kk < 16; ++kk)
            asm volatile("" : "+v"(bf[c][kk]));   // pin (no remat)

    // ---- input-projection B slice (wave 3; K = 96 padded)
    f16x8 bp[2][3];
    if (kq == 3) {
        #pragma unroll
        for (int c = 0; c < 2; ++c) {
            const f16* base = Bp + (size_t)(cg * 32 + c * 16 + fr) * NUP + kg * 8;
            #pragma unroll
            for (int k2 = 0; k2 < 3; ++k2) {
                bp[c][k2] = *(const f16x8*)(base + k2 * 32);
                asm volatile("" : "+v"(bp[c][k2]));
            }
        }
    }

    // ---- fp32 master state: wave kq owns tile (rt, ct)
    float rm[4];
    #pragma unroll
    for (int i = 0; i < 4; ++i)
        rm[i] = r0[(size_t)(rt * 16 + kg * 4 + i) * NR + cg * 32 + ct * 16 + fr];

    asm volatile("s_waitcnt vmcnt(0) lgkmcnt(0)" ::: "memory");
    __builtin_amdgcn_sched_barrier(0);

    for (int s = 0; s < NS; ++s) {
        const f16* cur = rbuf + (size_t)(s & 1) * NB * NR;
        f16*       nxt = rbuf + (size_t)((s + 1) & 1) * NB * NR;
        const int  tc  = tag_of_step(s);
        const int  tn  = tag_of_step(s + 1);
        const u64  tmask = 0x0001000100010001ull;
        const u64  texp  = tc ? tmask : 0ull;

        // ---- xq loads (wave 3): plain cached, compiler-managed
        f16x8 q0, q1, q2, q3, q4, q5;
        if (kq == 3) {
            const f16* xb0 = xp + ((size_t)s * NB + fr) * NUP + kg * 8;
            const f16* xb1 = xb0 + 16 * NUP;
            q0 = *(const f16x8*)(xb0);
            q1 = *(const f16x8*)(xb0 + 32);
            q2 = *(const f16x8*)(xb0 + 64);
            q3 = *(const f16x8*)(xb1);
            q4 = *(const f16x8*)(xb1 + 32);
            q5 = *(const f16x8*)(xb1 + 64);
        }

        // ---- speculative straight-line 16B sc0sc1 loads (issued ONCE)
        // xr[2*kk+rtl] = r[rtl*16+fr][kq*512 + kk*32 + kg*8 ..+8]
        f16x8 xr[32];
        const f16* rl0 = cur + (size_t)fr * NR + kq * 512 + kg * 8;
        const f16* rl1 = rl0 + 16 * NR;
        #define LDX(i, base, imm) asm volatile(                                \
            "global_load_dwordx4 %0, %1, off offset:" #imm " sc0 sc1"          \
            : "=v"(xr[i]) : "v"(base) : "memory")
        LDX(0,rl0,0);    LDX(1,rl1,0);    LDX(2,rl0,64);   LDX(3,rl1,64);
        LDX(4,rl0,128);  LDX(5,rl1,128);  LDX(6,rl0,192);  LDX(7,rl1,192);
        LDX(8,rl0,256);  LDX(9,rl1,256);  LDX(10,rl0,320); LDX(11,rl1,320);
        LDX(12,rl0,384); LDX(13,rl1,384); LDX(14,rl0,448); LDX(15,rl1,448);
        LDX(16,rl0,512); LDX(17,rl1,512); LDX(18,rl0,576); LDX(19,rl1,576);
        LDX(20,rl0,640); LDX(21,rl1,640); LDX(22,rl0,704); LDX(23,rl1,704);
        LDX(24,rl0,768); LDX(25,rl1,768); LDX(26,rl0,832); LDX(27,rl1,832);
        LDX(28,rl0,896); LDX(29,rl1,896); LDX(30,rl0,960); LDX(31,rl1,960);
        #undef LDX
        WAIT0;

        // ---- verify: one tag bit per 16B cell (cells are atomic publishes)
        int bad = 0;
        #pragma unroll
        for (int i = 0; i < 32; ++i) bad |= (TAGOF(xr[i]) ^ tc);

        if (__any(bad)) {
            // ---- cold slow path: bounded compiler-managed reload + recheck.
            // All fast-path defs retired (WAIT0 above), so overwriting xr here
            // joins only retired values -- no in-flight-register phis.
            int spins = 0;
            while (true) {
                u64 xs[64];
                #pragma unroll
                for (int kk = 0; kk < 16; ++kk) {
                    const u64* p0 = (const u64*)(cur + (size_t)fr * NR
                                                 + kq * 512 + kk * 32 + kg * 8);
                    const u64* p1 = (const u64*)(cur + (size_t)(fr + 16) * NR
                                                 + kq * 512 + kk * 32 + kg * 8);
                    xs[4*kk+0] = __hip_atomic_load(p0,   __ATOMIC_RELAXED, __HIP_MEMORY_SCOPE_AGENT);
                    xs[4*kk+1] = __hip_atomic_load(p0+1, __ATOMIC_RELAXED, __HIP_MEMORY_SCOPE_AGENT);
                    xs[4*kk+2] = __hip_atomic_load(p1,   __ATOMIC_RELAXED, __HIP_MEMORY_SCOPE_AGENT);
                    xs[4*kk+3] = __hip_atomic_load(p1+1, __ATOMIC_RELAXED, __HIP_MEMORY_SCOPE_AGENT);
                }
                u64 b = 0;
                #pragma unroll
                for (int i = 0; i < 64; ++i) b |= (xs[i] ^ texp) & tmask;
                if (__all(b == 0ull) || ++spins > RETRY_BOUND) {
                    #pragma unroll
                    for (int kk = 0; kk < 16; ++kk) {
                        xr[2*kk+0] = pack16(xs[4*kk+0], xs[4*kk+1]);
                        xr[2*kk+1] = pack16(xs[4*kk+2], xs[4*kk+3]);
                    }
                    break;
                }
                __builtin_amdgcn_s_sleep(2);
            }
        }

        // ---- MFMAs
        f32x4 a00 = {0,0,0,0}, a01 = {0,0,0,0}, a10 = {0,0,0,0}, a11 = {0,0,0,0};
        if (kq == 3) {   // bu projection (K = 96)
            a00 = MFMA(q0, bp[0][0], a00); a01 = MFMA(q0, bp[1][0], a01);
            a10 = MFMA(q3, bp[0][0], a10); a11 = MFMA(q3, bp[1][0], a11);
            a00 = MFMA(q1, bp[0][1], a00); a01 = MFMA(q1, bp[1][1], a01);
            a10 = MFMA(q4, bp[0][1], a10); a11 = MFMA(q4, bp[1][1], a11);
            a00 = MFMA(q2, bp[0][2], a00); a01 = MFMA(q2, bp[1][2], a01);
            a10 = MFMA(q5, bp[0][2], a10); a11 = MFMA(q5, bp[1][2], a11);
        }
        #pragma unroll
        for (int kk = 0; kk < 16; ++kk) {
            a00 = MFMA(xr[2*kk+0], bf[0][kk], a00);
            a01 = MFMA(xr[2*kk+0], bf[1][kk], a01);
            a10 = MFMA(xr[2*kk+1], bf[0][kk], a10);
            a11 = MFMA(xr[2*kk+1], bf[1][kk], a11);
        }

        // ---- cross-wave K reduction
        lds_part[kq][0][lane] = a00;
        lds_part[kq][1][lane] = a01;
        lds_part[kq][2][lane] = a10;
        lds_part[kq][3][lane] = a11;
        __syncthreads();   // join: all 4 waves verified all 64 producers

        const int tile = kq;
        f32x4 sum = lds_part[0][tile][lane] + lds_part[1][tile][lane]
                  + lds_part[2][tile][lane] + lds_part[3][tile][lane];

        float rn[4];
        #pragma unroll
        for (int i = 0; i < 4; ++i) {
            float v = (1.0f - ALPHA) * rm[i] + ALPHA * tanhf(sum[i] + SIGMA_B);
            rm[i] = v;
            rn[i] = v;
            f16 h = (f16)v;
            unsigned short b = __builtin_bit_cast(unsigned short, h);
            b = (unsigned short)((b & ~1u) | (unsigned)tn);
            lds_r[(rt * 16 + kg * 4 + i) * 40 + ct * 16 + fr] = __builtin_bit_cast(f16, b);
        }
        __syncthreads();   // lds_r complete

        // ---- publish: fire-and-forget tagged 16B cells (no ack, no flag)
        if (s != NS - 1 && tid < 128) {
            int row = tid >> 2, seg = tid & 3;
            f16x8 v = *(const f16x8*)&lds_r[row * 40 + seg * 8];
            f16* pp = nxt + (size_t)row * NR + cg * 32 + seg * 8;
            asm volatile("global_store_dwordx4 %0, %1, off sc0 sc1"
                         :: "v"(pp), "v"(v) : "memory");
        }

        // ---- output stream (off the critical path)
        {
            float* po = out + ((size_t)(rt * 16 + kg * 4) * NS + s) * NR
                        + cg * 32 + ct * 16 + fr;
            __builtin_nontemporal_store(rn[0], po + 0ull * NS * NR);
            __builtin_nontemporal_store(rn[1], po + 1ull * NS * NR);
            __builtin_nontemporal_store(rn[2], po + 2ull * NS * NR);
            __builtin_nontemporal_store(rn[3], po + 3ull * NS * NR);
        }
    }

    // ---- final state r_final (1, 32, 2048)
    #pragma unroll
    for (int i = 0; i < 4; ++i)
        out[(size_t)NB * NS * NR
            + (size_t)(rt * 16 + kg * 4 + i) * NR + cg * 32 + ct * 16 + fr] = rm[i];
}

extern "C" void kernel_launch(void* const* d_in, const int* in_sizes, int n_in,
                              void* d_out, int out_size, void* d_ws, size_t ws_size,
                              hipStream_t stream)
{
    const float* input = (const float*)d_in[0];
    const float* r0    = (const float*)d_in[1];
    const float* A     = (const float*)d_in[2];
    const float* B     = (const float*)d_in[3];
    float* out = (float*)d_out;
    char* ws = (char*)d_ws;

    f16* Af = (f16*)(ws + OFF_AF);
    f16* xp = (f16*)(ws + OFF_XP);
    f16* Bp = (f16*)(ws + OFF_BP);
    f16* rb = (f16*)(ws + OFF_RB);

    // No flags, no memset: tagged publishes are self-validating across replays.
    prep_kernel<<<2048, 256, 0, stream>>>(input, r0, A, B, Af, xp, Bp, rb);
    scan_kernel<<<NWG, 256, 0, stream>>>(out, r0, Af, xp, Bp, rb);
}

// Round 14
// 7455.615 us; speedup vs baseline: 1.5632x; 1.5632x over previous
//
#include <hip/hip_runtime.h>
#include <cmath>

typedef _Float16 f16;
typedef _Float16 f16x8 __attribute__((ext_vector_type(8)));
typedef float f32x4 __attribute__((ext_vector_type(4)));
typedef int i32x4 __attribute__((ext_vector_type(4)));
typedef unsigned long long u64;

#define NR 2048
#define NU 80
#define NUP 96          // NU padded to multiple of 32
#define NB 32           // batch
#define NS 1024         // seq len
#define NWG 64          // one WG per 32-col slice, all 32 batch rows
#define ALPHA 0.6f
#define SIGMA_B 1.6f
#define POLL_BOUND (1 << 20)   // detect spin cap
#define RETRY_BOUND (1 << 16)  // slow-path cap

// workspace layout (bytes)
#define OFF_AF   0ull                              // A fp16 [2048][2048] : 8 MiB
#define OFF_XP   (OFF_AF + (size_t)NR*NR*2)        // input fp16 [s][b][96] : 6 MiB
#define OFF_BP   (OFF_XP + (size_t)NS*NB*NUP*2)    // B fp16 [2048][96]
#define OFF_RB   (OFF_BP + (size_t)NR*NUP*2)       // r bufs fp16 [2][NB][NR] : 256 KiB

// step-parity tag in bit0 of EVERY published f16 (r12-validated).
// t(s) = ((s>>1)+1)&1 : slot occupants at steps s and s-2 always differ; prep
// tags r0 with t(0)=1; 0xAA poison (bit0=0) and replay leftovers are stale.
__device__ __host__ inline int tag_of_step(int s) { return (((s >> 1) + 1) & 1); }

__global__ void prep_kernel(const float* __restrict__ input,
                            const float* __restrict__ r0,
                            const float* __restrict__ A,
                            const float* __restrict__ B,
                            f16* __restrict__ Af, f16* __restrict__ xp,
                            f16* __restrict__ Bp, f16* __restrict__ rb)
{
    const int stride = gridDim.x * blockDim.x;
    const int tid = blockIdx.x * blockDim.x + threadIdx.x;
    for (int i = tid; i < NR * NR; i += stride) Af[i] = (f16)A[i];
    for (int i = tid; i < NS * NB * NUP; i += stride) {
        int u = i % NUP; int sb = i / NUP; int b = sb % NB; int s = sb / NB;
        xp[i] = (u < NU) ? (f16)input[((size_t)b * NS + s) * NU + u] : (f16)0.0f;
    }
    for (int i = tid; i < NR * NUP; i += stride) {
        int u = i % NUP; int j = i / NUP;
        Bp[i] = (u < NU) ? (f16)B[j * NU + u] : (f16)0.0f;
    }
    // r0 -> buffer 0, tagged t(0)=1
    for (int i = tid; i < NB * NR; i += stride) {
        f16 h = (f16)r0[i];
        unsigned short b = __builtin_bit_cast(unsigned short, h);
        b = (unsigned short)((b & ~1u) | 1u);
        rb[i] = __builtin_bit_cast(f16, b);
    }
}

#define MFMA(va, vb, vc) __builtin_amdgcn_mfma_f32_16x16x32_f16(va, vb, vc, 0, 0, 0)
#define TAGOF(v) (__builtin_bit_cast(i32x4, v).x & 1)
// Rule #18: bare s_waitcnt needs a following sched_barrier(0).
#define WAIT0 do { asm volatile("s_waitcnt vmcnt(0)" ::: "memory");            \
                   __builtin_amdgcn_sched_barrier(0); } while (0)

__device__ inline f16x8 pack16(u64 lo, u64 hi) {
    u64 t[2] = { lo, hi };
    f16x8 r;
    __builtin_memcpy(&r, t, 16);
    return r;
}

// Detect-then-speculate tag-validated device-scope scan.
// 64 WGs x 256 threads; WG cg owns output cols [32cg,32cg+32) for all 32 batch
// rows. Wave kq consumes r cols [512kq,512kq+512) (producers 16kq..16kq+16)
// and owns output tile (rt=kq>>1, ct=kq&1); master state in f32 registers.
// Per step: detect = poll 16 producer HEAD cells (compiler atomics, loop-safe)
// -> straight-line 32x16B sc0sc1 asm loads issued ONCE -> WAIT0 -> verify one
// tag bit per 16B cell (publishes are whole-dwordx4 => per-cell atomic) ->
// [rare slow path: bounded C++ atomic reload, overwrites after retire] ->
// 64+3 MFMAs -> LDS reduce -> tanh -> tagged 16B fire-and-forget publish
// (NO ack, NO flag -- the two CP hops deleted vs the r4 flag protocol).
// Lap-safety: a WG publishes s+1 only after its 4 waves verified step-s tags
// from ALL 64 WGs (joined at the reduce barrier); a producer's step-s tags are
// stored only after its step-(s-1) reads completed -> transitive gating.
__global__ __launch_bounds__(256, 1) void scan_kernel(
    float* __restrict__ out,
    const float* __restrict__ r0,
    const f16* __restrict__ Af, const f16* __restrict__ xp,
    const f16* __restrict__ Bp, f16* __restrict__ rbuf)
{
    const int tid  = threadIdx.x;
    const int lane = tid & 63;
    const int kq   = tid >> 6;      // K-quarter; owned tile = (kq>>1, kq&1)
    const int cg   = blockIdx.x;
    const int rt   = kq >> 1;
    const int ct   = kq & 1;
    const int fr   = lane & 15;
    const int kg   = lane >> 4;

    __shared__ f32x4 lds_part[4][4][64];   // [wave][tile][lane]
    __shared__ f16   lds_r[32 * 40];       // stride 40 halves (80B, 16B-aligned)

    // ---- A-slice -> registers (B^T fragment layout), 2 col-tiles x 16 k-frags
    f16x8 bf[2][16];
    #pragma unroll
    for (int c = 0; c < 2; ++c) {
        const f16* base = Af + (size_t)(cg * 32 + c * 16 + fr) * NR + kq * 512 + kg * 8;
        #pragma unroll
        for (int kk = 0; kk < 16; ++kk)
            bf[c][kk] = *(const f16x8*)(base + kk * 32);
    }
    #pragma unroll
    for (int c = 0; c < 2; ++c)
        #pragma unroll
        for (int kk = 0; kk < 16; ++kk)
            asm volatile("" : "+v"(bf[c][kk]));   // pin (no remat)

    // ---- input-projection B slice (wave 3; K = 96 padded)
    f16x8 bp[2][3];
    if (kq == 3) {
        #pragma unroll
        for (int c = 0; c < 2; ++c) {
            const f16* base = Bp + (size_t)(cg * 32 + c * 16 + fr) * NUP + kg * 8;
            #pragma unroll
            for (int k2 = 0; k2 < 3; ++k2) {
                bp[c][k2] = *(const f16x8*)(base + k2 * 32);
                asm volatile("" : "+v"(bp[c][k2]));
            }
        }
    }

    // ---- fp32 master state: wave kq owns tile (rt, ct)
    float rm[4];
    #pragma unroll
    for (int i = 0; i < 4; ++i)
        rm[i] = r0[(size_t)(rt * 16 + kg * 4 + i) * NR + cg * 32 + ct * 16 + fr];

    asm volatile("s_waitcnt vmcnt(0) lgkmcnt(0)" ::: "memory");
    __builtin_amdgcn_sched_barrier(0);

    for (int s = 0; s < NS; ++s) {
        const f16* cur = rbuf + (size_t)(s & 1) * NB * NR;
        f16*       nxt = rbuf + (size_t)((s + 1) & 1) * NB * NR;
        const int  tc  = tag_of_step(s);
        const int  tn  = tag_of_step(s + 1);
        const u64  tmask = 0x0001000100010001ull;
        const u64  texp  = tc ? tmask : 0ull;

        // ---- xq loads (wave 3): plain cached, issued before detect (overlap)
        f16x8 q0, q1, q2, q3, q4, q5;
        if (kq == 3) {
            const f16* xb0 = xp + ((size_t)s * NB + fr) * NUP + kg * 8;
            const f16* xb1 = xb0 + 16 * NUP;
            q0 = *(const f16x8*)(xb0);
            q1 = *(const f16x8*)(xb0 + 32);
            q2 = *(const f16x8*)(xb0 + 64);
            q3 = *(const f16x8*)(xb1);
            q4 = *(const f16x8*)(xb1 + 32);
            q5 = *(const f16x8*)(xb1 + 64);
        }

        // ---- detect: lanes 0..15 poll producer (kq*16+lane)'s head dword
        // (compiler-managed atomic loads: loop-safe; r12-validated)
        if (s) {
            const int* pc = (const int*)(cur + kq * 512 + (lane & 15) * 32);
            int spins = 0;
            while (true) {
                int w = tc;
                if (lane < 16)
                    w = __hip_atomic_load(pc, __ATOMIC_RELAXED,
                                          __HIP_MEMORY_SCOPE_AGENT) & 1;
                if (__all(w == tc)) break;
                if (++spins > POLL_BOUND) break;   // escape: no deadlock
                __builtin_amdgcn_s_sleep(1);
            }
        }

        // ---- straight-line 16B sc0sc1 loads (issued ONCE; proven-safe shape)
        // xr[2*kk+rtl] = r[rtl*16+fr][kq*512 + kk*32 + kg*8 ..+8]
        f16x8 xr[32];
        const f16* rl0 = cur + (size_t)fr * NR + kq * 512 + kg * 8;
        const f16* rl1 = rl0 + 16 * NR;
        #define LDX(i, base, imm) asm volatile(                                \
            "global_load_dwordx4 %0, %1, off offset:" #imm " sc0 sc1"          \
            : "=v"(xr[i]) : "v"(base) : "memory")
        LDX(0,rl0,0);    LDX(1,rl1,0);    LDX(2,rl0,64);   LDX(3,rl1,64);
        LDX(4,rl0,128);  LDX(5,rl1,128);  LDX(6,rl0,192);  LDX(7,rl1,192);
        LDX(8,rl0,256);  LDX(9,rl1,256);  LDX(10,rl0,320); LDX(11,rl1,320);
        LDX(12,rl0,384); LDX(13,rl1,384); LDX(14,rl0,448); LDX(15,rl1,448);
        LDX(16,rl0,512); LDX(17,rl1,512); LDX(18,rl0,576); LDX(19,rl1,576);
        LDX(20,rl0,640); LDX(21,rl1,640); LDX(22,rl0,704); LDX(23,rl1,704);
        LDX(24,rl0,768); LDX(25,rl1,768); LDX(26,rl0,832); LDX(27,rl1,832);
        LDX(28,rl0,896); LDX(29,rl1,896); LDX(30,rl0,960); LDX(31,rl1,960);
        #undef LDX
        WAIT0;

        // ---- verify: one tag bit per 16B cell
        int bad = 0;
        #pragma unroll
        for (int i = 0; i < 32; ++i) bad |= (TAGOF(xr[i]) ^ tc);

        if (__any(bad)) {
            // ---- rare slow path: bounded compiler-managed reload + recheck.
            // Fast-path defs retired (WAIT0), so overwriting xr joins only
            // retired values -- no in-flight-register phis.
            int spins = 0;
            while (true) {
                u64 xs[64];
                #pragma unroll
                for (int kk = 0; kk < 16; ++kk) {
                    const u64* p0 = (const u64*)(cur + (size_t)fr * NR
                                                 + kq * 512 + kk * 32 + kg * 8);
                    const u64* p1 = (const u64*)(cur + (size_t)(fr + 16) * NR
                                                 + kq * 512 + kk * 32 + kg * 8);
                    xs[4*kk+0] = __hip_atomic_load(p0,   __ATOMIC_RELAXED, __HIP_MEMORY_SCOPE_AGENT);
                    xs[4*kk+1] = __hip_atomic_load(p0+1, __ATOMIC_RELAXED, __HIP_MEMORY_SCOPE_AGENT);
                    xs[4*kk+2] = __hip_atomic_load(p1,   __ATOMIC_RELAXED, __HIP_MEMORY_SCOPE_AGENT);
                    xs[4*kk+3] = __hip_atomic_load(p1+1, __ATOMIC_RELAXED, __HIP_MEMORY_SCOPE_AGENT);
                }
                u64 b = 0;
                #pragma unroll
                for (int i = 0; i < 64; ++i) b |= (xs[i] ^ texp) & tmask;
                if (__all(b == 0ull) || ++spins > RETRY_BOUND) {
                    #pragma unroll
                    for (int kk = 0; kk < 16; ++kk) {
                        xr[2*kk+0] = pack16(xs[4*kk+0], xs[4*kk+1]);
                        xr[2*kk+1] = pack16(xs[4*kk+2], xs[4*kk+3]);
                    }
                    break;
                }
                __builtin_amdgcn_s_sleep(2);
            }
        }

        // ---- MFMAs
        f32x4 a00 = {0,0,0,0}, a01 = {0,0,0,0}, a10 = {0,0,0,0}, a11 = {0,0,0,0};
        if (kq == 3) {   // bu projection (K = 96)
            a00 = MFMA(q0, bp[0][0], a00); a01 = MFMA(q0, bp[1][0], a01);
            a10 = MFMA(q3, bp[0][0], a10); a11 = MFMA(q3, bp[1][0], a11);
            a00 = MFMA(q1, bp[0][1], a00); a01 = MFMA(q1, bp[1][1], a01);
            a10 = MFMA(q4, bp[0][1], a10); a11 = MFMA(q4, bp[1][1], a11);
            a00 = MFMA(q2, bp[0][2], a00); a01 = MFMA(q2, bp[1][2], a01);
            a10 = MFMA(q5, bp[0][2], a10); a11 = MFMA(q5, bp[1][2], a11);
        }
        #pragma unroll
        for (int kk = 0; kk < 16; ++kk) {
            a00 = MFMA(xr[2*kk+0], bf[0][kk], a00);
            a01 = MFMA(xr[2*kk+0], bf[1][kk], a01);
            a10 = MFMA(xr[2*kk+1], bf[0][kk], a10);
            a11 = MFMA(xr[2*kk+1], bf[1][kk], a11);
        }

        // ---- cross-wave K reduction
        lds_part[kq][0][lane] = a00;
        lds_part[kq][1][lane] = a01;
        lds_part[kq][2][lane] = a10;
        lds_part[kq][3][lane] = a11;
        __syncthreads();   // join: all 4 waves verified all 64 producers

        const int tile = kq;
        f32x4 sum = lds_part[0][tile][lane] + lds_part[1][tile][lane]
                  + lds_part[2][tile][lane] + lds_part[3][tile][lane];

        float rn[4];
        #pragma unroll
        for (int i = 0; i < 4; ++i) {
            float v = (1.0f - ALPHA) * rm[i] + ALPHA * tanhf(sum[i] + SIGMA_B);
            rm[i] = v;
            rn[i] = v;
            f16 h = (f16)v;
            unsigned short b = __builtin_bit_cast(unsigned short, h);
            b = (unsigned short)((b & ~1u) | (unsigned)tn);
            lds_r[(rt * 16 + kg * 4 + i) * 40 + ct * 16 + fr] = __builtin_bit_cast(f16, b);
        }
        __syncthreads();   // lds_r complete

        // ---- publish: fire-and-forget tagged 16B cells (no ack, no flag)
        if (s != NS - 1 && tid < 128) {
            int row = tid >> 2, seg = tid & 3;
            f16x8 v = *(const f16x8*)&lds_r[row * 40 + seg * 8];
            f16* pp = nxt + (size_t)row * NR + cg * 32 + seg * 8;
            asm volatile("global_store_dwordx4 %0, %1, off sc0 sc1"
                         :: "v"(pp), "v"(v) : "memory");
        }

        // ---- output stream (off the critical path)
        {
            float* po = out + ((size_t)(rt * 16 + kg * 4) * NS + s) * NR
                        + cg * 32 + ct * 16 + fr;
            __builtin_nontemporal_store(rn[0], po + 0ull * NS * NR);
            __builtin_nontemporal_store(rn[1], po + 1ull * NS * NR);
            __builtin_nontemporal_store(rn[2], po + 2ull * NS * NR);
            __builtin_nontemporal_store(rn[3], po + 3ull * NS * NR);
        }
    }

    // ---- final state r_final (1, 32, 2048)
    #pragma unroll
    for (int i = 0; i < 4; ++i)
        out[(size_t)NB * NS * NR
            + (size_t)(rt * 16 + kg * 4 + i) * NR + cg * 32 + ct * 16 + fr] = rm[i];
}

extern "C" void kernel_launch(void* const* d_in, const int* in_sizes, int n_in,
                              void* d_out, int out_size, void* d_ws, size_t ws_size,
                              hipStream_t stream)
{
    const float* input = (const float*)d_in[0];
    const float* r0    = (const float*)d_in[1];
    const float* A     = (const float*)d_in[2];
    const float* B     = (const float*)d_in[3];
    float* out = (float*)d_out;
    char* ws = (char*)d_ws;

    f16* Af = (f16*)(ws + OFF_AF);
    f16* xp = (f16*)(ws + OFF_XP);
    f16* Bp = (f16*)(ws + OFF_BP);
    f16* rb = (f16*)(ws + OFF_RB);

    // No flags, no memset: tagged publishes are self-validating across replays.
    prep_kernel<<<2048, 256, 0, stream>>>(input, r0, A, B, Af, xp, Bp, rb);
    scan_kernel<<<NWG, 256, 0, stream>>>(out, r0, Af, xp, Bp, rb);
}